// Round 3
// baseline (47.840 us; speedup 1.0000x reference)
//
#include <hip/hip_runtime.h>

// Problem constants (fixed by reference setup_inputs)
constexpr int B = 16, H = 1024, W = 1024, N = 2000;
constexpr int HW = H * W;                       // 1,048,576
constexpr long long TOT = (long long)B * HW;    // 16,777,216
constexpr float SMOOTH = 1e-6f;

typedef float f32x4 __attribute__((ext_vector_type(4)));
typedef unsigned int u32x4 __attribute__((ext_vector_type(4)));

// Workspace layout:
//   [0, 2MB)            : gt bitmask (uint32 words)
//   [2MB, 2MB+48KB)     : per-block partials part[q*NBLOCKS + blk], q=0..5
constexpr size_t MASK_WORDS = (size_t)B * HW / 32;   // 524,288 words
constexpr size_t MASK_BYTES = MASK_WORDS * 4;        // 2 MB

constexpr int BLOCKS_PER_BATCH = 128;
constexpr int NBLOCKS = B * BLOCKS_PER_BATCH;        // 2048
constexpr int THREADS = 256;
constexpr int UNROLL = 8;

// Disk stencil (13 taps, radius 2), packed as nibbles (value+2), k = nibble idx.
// dy: {-2,-1,-1,-1,0,0,0,0,0,1,1,1,2}  dx: {0,-1,0,1,-2,-1,0,1,2,-1,0,1,0}
constexpr unsigned long long DY_PACK = 0x4333222221110ULL;
constexpr unsigned long long DX_PACK = 0x2321432103212ULL;

// ---------------------------------------------------------------------------
// Zero the mask. 512 blocks x 256 threads x 16B = 2 MB.
// (round 1 lesson: no agent-scope fence fusion — cross-XCD L2 wb/inv storms
//  made mainpass 14x slower. Kernel-boundary handoff only.)
// ---------------------------------------------------------------------------
__global__ __launch_bounds__(256)
void zero_kernel(u32x4* __restrict__ maskv) {
    int t = blockIdx.x * 256 + threadIdx.x;
    maskv[t] = (u32x4)(0u);
}

// ---------------------------------------------------------------------------
// Raster: one thread per (point, stencil tap). grid = (ceil(B*N/256), 13).
// Round 2 version had 125 blocks x 13 serialized scattered atomics per thread
// (~2 waves/CU, latency-bound). This gives 13x the parallelism; the stencil
// offset is wave-uniform (blockIdx.y) -> scalar regs, zero divergence there.
// ---------------------------------------------------------------------------
__global__ __launch_bounds__(256)
void raster_kernel(const int* __restrict__ pts,
                   unsigned int* __restrict__ mask) {
    const int k = blockIdx.y;                       // 0..12, wave-uniform
    const int dyk = (int)((DY_PACK >> (4 * k)) & 15) - 2;
    const int dxk = (int)((DX_PACK >> (4 * k)) & 15) - 2;

    int t = blockIdx.x * 256 + threadIdx.x;         // point id
    if (t >= B * N) return;
    int b = t / N;
    int x = pts[2 * t + 0];
    int y = pts[2 * t + 1];
    int cx = x >> 2;   // floor div STRIDE=4
    int cy = y >> 2;
    if (cx < 0 || cx >= W || cy < 0 || cy >= H) return;

    int yy = cy + dyk;
    int xx = cx + dxk;
    if (yy >= 0 && yy < H && xx >= 0 && xx < W) {
        unsigned int idx = (unsigned int)b * HW + (unsigned int)yy * W
                         + (unsigned int)xx;
        atomicOr(&mask[idx >> 5], 1u << (idx & 31));
    }
}

__device__ inline float wave_reduce(float v) {
#pragma unroll
    for (int o = 32; o > 0; o >>= 1) v += __shfl_down(v, o, 64);
    return v;
}

__global__ __launch_bounds__(THREADS)
void mainpass_kernel(const float* __restrict__ logits,
                     const unsigned int* __restrict__ mask,
                     float* __restrict__ part) {
    const int blk = blockIdx.x;
    const int b = blk / BLOCKS_PER_BATCH;
    const int chunk = blk % BLOCKS_PER_BATCH;
    const int base_v = b * (HW / 4) + chunk * (UNROLL * THREADS);
    const int tid = threadIdx.x;

    const f32x4* __restrict__ vlog = reinterpret_cast<const f32x4*>(logits);

    f32x4 xv[UNROLL];
    unsigned int mw[UNROLL];
#pragma unroll
    for (int it = 0; it < UNROLL; ++it) {
        int v = base_v + it * THREADS + tid;
        xv[it] = vlog[v];
        mw[it] = mask[(unsigned int)v >> 3];
    }

    float sA = 0.f, sBg = 0.f, sCg = 0.f, si = 0.f, spr = 0.f, sg = 0.f;

#pragma unroll
    for (int it = 0; it < UNROLL; ++it) {
        int v = base_v + it * THREADS + tid;
        unsigned int bits = mw[it] >> ((v & 7) * 4);   // low 4 bits valid
#pragma unroll
        for (int j = 0; j < 4; ++j) {
            float x = xv[it][j];
            float g = (float)((bits >> j) & 1u);
            float ax = fabsf(x);
            float t = __builtin_amdgcn_exp2f(-1.44269504f * ax);  // e^-|x|
            float u = 1.0f + t;
            float l = __builtin_amdgcn_logf(u) * 0.69314718f;     // log(1+t)
            float sp = l + fmaxf(x, 0.f);                         // softplus(x)
            float r = __builtin_amdgcn_rcpf(u);
            float prob = r * ((x >= 0.f) ? 1.0f : t);             // sigmoid(x)
            sA += sp;
            sBg += g * sp;
            sCg += g * x;
            si += g * prob;
            spr += prob;
            sg += g;
        }
    }

    __shared__ float red[4][6];
    int lane = threadIdx.x & 63;
    int wv = threadIdx.x >> 6;
    sA = wave_reduce(sA);
    sBg = wave_reduce(sBg);
    sCg = wave_reduce(sCg);
    si = wave_reduce(si);
    spr = wave_reduce(spr);
    sg = wave_reduce(sg);
    if (lane == 0) {
        red[wv][0] = sA; red[wv][1] = sBg; red[wv][2] = sCg;
        red[wv][3] = si; red[wv][4] = spr; red[wv][5] = sg;
    }
    __syncthreads();
    if (threadIdx.x == 0) {
        float a[6] = {0, 0, 0, 0, 0, 0};
#pragma unroll
        for (int w = 0; w < 4; ++w)
#pragma unroll
            for (int q = 0; q < 6; ++q) a[q] += red[w][q];
        // Contention-free per-block partial stores (no atomics anywhere).
#pragma unroll
        for (int q = 0; q < 6; ++q) part[q * NBLOCKS + blk] = a[q];
    }
}

__global__ __launch_bounds__(256)
void reduce_finalize_kernel(const float* __restrict__ part,
                            float* __restrict__ out) {
    const int tid = threadIdx.x;
    const int lane = tid & 63;
    const int wv = tid >> 6;

    // ---- global sums (q = 0,1,2) ----
    float a0 = 0.f, a1 = 0.f, a2 = 0.f;
#pragma unroll
    for (int k = 0; k < NBLOCKS / 256; ++k) {
        int i = tid + 256 * k;
        a0 += part[0 * NBLOCKS + i];
        a1 += part[1 * NBLOCKS + i];
        a2 += part[2 * NBLOCKS + i];
    }
    a0 = wave_reduce(a0);
    a1 = wave_reduce(a1);
    a2 = wave_reduce(a2);
    __shared__ float redg[4][3];
    if (lane == 0) { redg[wv][0] = a0; redg[wv][1] = a1; redg[wv][2] = a2; }

    // ---- per-batch sums (q = 3,4,5): 16 threads per batch ----
    int b = tid >> 4;        // 0..15
    int j = tid & 15;        // 0..15
    float p3 = 0.f, p4 = 0.f, p5 = 0.f;
#pragma unroll
    for (int k = 0; k < BLOCKS_PER_BATCH / 16; ++k) {
        int idx = b * BLOCKS_PER_BATCH + j + 16 * k;
        p3 += part[3 * NBLOCKS + idx];
        p4 += part[4 * NBLOCKS + idx];
        p5 += part[5 * NBLOCKS + idx];
    }
#pragma unroll
    for (int m = 1; m < 16; m <<= 1) {
        p3 += __shfl_xor(p3, m, 64);
        p4 += __shfl_xor(p4, m, 64);
        p5 += __shfl_xor(p5, m, 64);
    }
    __shared__ float sI[16], sP[16], sG[16];
    if (j == 0) { sI[b] = p3; sP[b] = p4; sG[b] = p5; }
    __syncthreads();

    if (tid == 0) {
        float A = 0.f, Bg = 0.f, Cg = 0.f;
#pragma unroll
        for (int w = 0; w < 4; ++w) {
            A += redg[w][0]; Bg += redg[w][1]; Cg += redg[w][2];
        }
        float S1 = Bg - Cg;          // sum g*softplus(-x)
        float S2 = A - Bg;           // sum (1-g)*softplus(x)
        float pos = 0.f;
#pragma unroll
        for (int bb = 0; bb < B; ++bb) pos += sG[bb];
        float neg = (float)TOT - pos;
        float pw = neg / (pos + SMOOTH);
        float bce = (pw * S1 + S2) / (float)TOT;
        float dsum = 0.f;
#pragma unroll
        for (int bb = 0; bb < B; ++bb) {
            dsum += (2.f * sI[bb] + SMOOTH) / (sP[bb] + sG[bb] + SMOOTH);
        }
        float dice = 1.f - dsum / (float)B;
        out[0] = 0.5f * bce + 0.5f * dice;
    }
}

extern "C" void kernel_launch(void* const* d_in, const int* in_sizes, int n_in,
                              void* d_out, int out_size, void* d_ws, size_t ws_size,
                              hipStream_t stream) {
    const float* logits = (const float*)d_in[0];
    const int* pts = (const int*)d_in[1];
    unsigned int* mask = (unsigned int*)d_ws;
    float* part = (float*)((char*)d_ws + MASK_BYTES);

    // Custom wide zero of the mask (no hipMemsetAsync / rocclr fill).
    zero_kernel<<<(int)(MASK_WORDS / 4 / 256), 256, 0, stream>>>(
        reinterpret_cast<u32x4*>(mask));

    // One thread per (point, stencil tap): 13x the parallelism of round 2.
    dim3 rgrid((B * N + 255) / 256, 13);
    raster_kernel<<<rgrid, 256, 0, stream>>>(pts, mask);

    mainpass_kernel<<<NBLOCKS, THREADS, 0, stream>>>(logits, mask, part);

    reduce_finalize_kernel<<<1, 256, 0, stream>>>(part, (float*)d_out);
}